// Round 5
// baseline (108.081 us; speedup 1.0000x reference)
//
#include <hip/hip_runtime.h>
#include <hip/hip_bf16.h>
#include <math.h>

#define BB 4
#define LL 1024
#define EE 1024
#define HH 16
#define DD 64
#define NCH 8
#define CHROWS 128   // LL / NCH
#define K2C 0.04508422002777998f   // log2(e)/32
#define THRL 177.0f                // 8 / K2C : defer-max threshold in logit units

typedef __attribute__((ext_vector_type(8))) short short8;
typedef __attribute__((ext_vector_type(4))) float f32x4;
typedef __attribute__((ext_vector_type(16))) float f32x16;
typedef __attribute__((ext_vector_type(4))) int int4v;

static __device__ __forceinline__ unsigned short bfbits(float x) {
    __hip_bfloat16 h = __float2bfloat16(x);
    return *(unsigned short*)&h;
}

#define CVTPK(dst, lo_, hi_) \
    asm("v_cvt_pk_bf16_f32 %0, %1, %2" : "=v"(dst) : "v"(lo_), "v"(hi_))
#define PLSWAP(x_, y_) \
    asm("v_permlane32_swap_b32 %0, %1" : "+v"(x_), "+v"(y_))

// ---------------------------------------------------------------------------
// Kernel 1: grouped 3x3 conv over (l, d) per head, + bias -> bf16 qcb[bh][l][d]
// ---------------------------------------------------------------------------
__global__ __launch_bounds__(256) void conv_kernel(
    const float* __restrict__ query,
    const float* __restrict__ conv_w,
    const float* __restrict__ conv_b,
    __hip_bfloat16* __restrict__ qcb) {
    int tid = threadIdx.x;
    int d = tid & 63;
    int lr = tid >> 6;
    int tile = blockIdx.x;                 // B*H*(L/4)
    int l0 = (tile & (LL / 4 - 1)) << 2;
    int bh = tile >> 8;
    int h = bh & (HH - 1);
    int b = bh >> 4;
    int l = l0 + lr;

    const float* w = conv_w + h * 9;
    float acc = conv_b[h];
    const float* qin = query + ((size_t)b * LL) * EE + h * DD;
    #pragma unroll
    for (int i = 0; i < 3; ++i) {
        int li = l + i - 1;
        if (li < 0 || li >= LL) continue;
        #pragma unroll
        for (int j = 0; j < 3; ++j) {
            int dj = d + j - 1;
            if (dj < 0 || dj >= DD) continue;
            acc += w[i * 3 + j] * qin[(size_t)li * EE + dj];
        }
    }
    qcb[((size_t)bh * LL + l) * DD + d] = __float2bfloat16(acc);
}

// ---------------------------------------------------------------------------
// Kernel 2a: per-chunk partial (max, sumexp) for keys column-softmax.
// ---------------------------------------------------------------------------
__global__ __launch_bounds__(256) void ksm_partial_kernel(
    const float* __restrict__ keys,
    const int* __restrict__ bern,
    float* __restrict__ pmax,
    float* __restrict__ psum) {
    __shared__ float sm[4][64], ss[4][64];
    int tid = threadIdx.x;
    int d = tid & 63;
    int seg = tid >> 6;
    int blk = blockIdx.x;
    int ch = blk & (NCH - 1);
    int bh = blk >> 3;
    int h = bh & (HH - 1);
    int b = bh >> 4;
    int r0 = ch * CHROWS + seg * 32;

    const float* kin = keys + ((size_t)b * LL + r0) * EE + h * DD + d;
    const int* bm = bern + (size_t)bh * LL + r0;

    float v[32];
    #pragma unroll
    for (int i = 0; i < 32; ++i) v[i] = kin[(size_t)i * EE];
    float m = -INFINITY;
    #pragma unroll
    for (int i = 0; i < 32; ++i)
        if (bm[i]) m = fmaxf(m, v[i]);
    float s = 0.f;
    #pragma unroll
    for (int i = 0; i < 32; ++i)
        if (bm[i]) s += __expf(v[i] - m);

    sm[seg][d] = m;
    ss[seg][d] = s;
    __syncthreads();
    if (seg == 0) {
        float M = sm[0][d];
        #pragma unroll
        for (int t = 1; t < 4; ++t) M = fmaxf(M, sm[t][d]);
        float S = 0.f;
        if (M > -INFINITY) {
            #pragma unroll
            for (int t = 0; t < 4; ++t)
                if (sm[t][d] > -INFINITY) S += ss[t][d] * __expf(sm[t][d] - M);
        }
        pmax[(size_t)blk * 64 + d] = M;
        psum[(size_t)blk * 64 + d] = S;
    }
}

// ---------------------------------------------------------------------------
// Kernel 2b: combine chunk partials; normalize chunk; write bf16 ksb.
// ---------------------------------------------------------------------------
__global__ __launch_bounds__(256) void ksm_final_kernel(
    const float* __restrict__ keys,
    const int* __restrict__ bern,
    const float* __restrict__ pmax,
    const float* __restrict__ psum,
    __hip_bfloat16* __restrict__ ksb) {
    int tid = threadIdx.x;
    int d = tid & 63;
    int seg = tid >> 6;
    int blk = blockIdx.x;
    int ch = blk & (NCH - 1);
    int bh = blk >> 3;
    int h = bh & (HH - 1);
    int b = bh >> 4;
    int r0 = ch * CHROWS + seg * 32;

    const float* pm = pmax + (size_t)bh * NCH * 64;
    const float* ps = psum + (size_t)bh * NCH * 64;
    float M = -INFINITY;
    #pragma unroll
    for (int c = 0; c < NCH; ++c) M = fmaxf(M, pm[c * 64 + d]);
    float S = 0.f;
    #pragma unroll
    for (int c = 0; c < NCH; ++c) {
        float mi = pm[c * 64 + d];
        if (mi > -INFINITY) S += ps[c * 64 + d] * __expf(mi - M);
    }
    float inv = 1.f / S;

    const float* kin = keys + ((size_t)b * LL + r0) * EE + h * DD + d;
    const int* bm = bern + (size_t)bh * LL + r0;
    __hip_bfloat16* kout = ksb + ((size_t)bh * LL + r0) * DD + d;
    #pragma unroll
    for (int i = 0; i < 32; ++i) {
        float val = bm[i] ? __expf(kin[(size_t)i * EE] - M) * inv : 0.f;
        kout[(size_t)i * DD] = __float2bfloat16(val);
    }
}

// ---------------------------------------------------------------------------
// Kernel 3: per-head value linear -> TRANSPOSED bf16 vt[bh][d][l]
// ---------------------------------------------------------------------------
__global__ __launch_bounds__(256) void vlin_kernel(
    const float* __restrict__ values,
    const float* __restrict__ Wv,
    __hip_bfloat16* __restrict__ vt) {
    __shared__ float WvS[64][65];
    __shared__ float vs[64][68];
    int tid = threadIdx.x;
    int tile = blockIdx.x;                 // B*H*(L/64) = 1024
    int lt = tile & 15;
    int bh = tile >> 4;
    int h = bh & (HH - 1);
    int b = bh >> 4;
    int l0 = lt * 64;

    for (int idx = tid; idx < 64 * 64; idx += 256)
        WvS[idx >> 6][idx & 63] = Wv[idx];
    const float* vin = values + ((size_t)b * LL + l0) * EE + h * DD;
    for (int idx = tid; idx < 1024; idx += 256) {
        int r = idx >> 4;
        int c4 = (idx & 15) << 2;
        *(float4*)&vs[r][c4] = *(const float4*)&vin[(size_t)r * EE + c4];
    }
    __syncthreads();

    int d = tid & 63;
    int r0 = (tid >> 6) * 16;
    float acc[16];
    #pragma unroll
    for (int r = 0; r < 16; ++r) acc[r] = 0.f;
    for (int k = 0; k < 64; ++k) {
        float wv = WvS[d][k];
        #pragma unroll
        for (int r = 0; r < 16; ++r) acc[r] += vs[r0 + r][k] * wv;
    }
    union { unsigned short us[16]; uint4 v[2]; } pk;
    #pragma unroll
    for (int r = 0; r < 16; ++r) pk.us[r] = bfbits(acc[r]);
    __hip_bfloat16* vo = vt + ((size_t)bh * DD + d) * LL + l0 + r0;
    *(uint4*)&vo[0] = pk.v[0];
    *(uint4*)&vo[8] = pk.v[1];
}

// ---------------------------------------------------------------------------
// Kernel 4: swapped-QK^T MFMA flash attention (32x32x16, in-register softmax).
// 4 waves x 32 q-rows = 128 q/block; 512 blocks; KVBLK=64 double-buffered.
// defer-max, hoisted V/mask loads, setprio around MFMA.
// ---------------------------------------------------------------------------
__global__ __launch_bounds__(256) void attn_mfma_kernel(
    const __hip_bfloat16* __restrict__ qcb,
    const __hip_bfloat16* __restrict__ ksb,
    const __hip_bfloat16* __restrict__ vtb,
    const int* __restrict__ pad,
    const int* __restrict__ cau,
    float* __restrict__ out) {
    __shared__ __align__(16) short KsS[2][4096];
    __shared__ __align__(16) short VtS[2][4096];
    __shared__ __align__(16) float OutS[4][32 * 36];
    __shared__ __align__(16) int smaskS[2][64];

    int tid = threadIdx.x;
    int lane = tid & 63;
    int w = tid >> 6;                  // 4 waves
    int q5 = lane & 31;
    int hi = lane >> 5;

    // XCD swizzle: 512 blocks; each XCD gets 64 consecutive swz = 8 bh (2MB KV in its L2)
    int bid = blockIdx.x;
    int swz = (bid & 7) * 64 + (bid >> 3);
    int bh = swz >> 3;
    int qb = swz & 7;
    int b = bh >> 4;
    int h = bh & 15;
    int q0w = qb * 128 + w * 32;

    const int* pb = pad + b * LL;
    const int* cb = cau + b * LL;

    // staging geometry: 256 threads x 2 its = 64 rows x 8 chunks of 8 bf16
    int srow = tid >> 3;               // 0..31 (it adds +32)
    int sch = tid & 7;
    int ssw = (sch ^ (srow & 7)) << 3;
    const __hip_bfloat16* kg = ksb + (size_t)bh * LL * DD + (size_t)srow * DD + ssw;
    const __hip_bfloat16* vg = vtb + (size_t)bh * DD * LL + (size_t)srow * LL + ssw;

    short8 Qf[4];
    {
        const __hip_bfloat16* qrow = qcb + ((size_t)bh * LL + q0w + q5) * DD + 8 * hi;
        #pragma unroll
        for (int i = 0; i < 4; ++i)
            Qf[i] = *(const short8*)(qrow + 16 * i);
    }

    // prologue: stage tile 0 into buf 0
    #pragma unroll
    for (int it = 0; it < 2; ++it) {
        __builtin_amdgcn_global_load_lds(
            (const __attribute__((address_space(1))) void*)(kg + (size_t)it * 32 * DD),
            (__attribute__((address_space(3))) void*)&KsS[0][(it * 4 + w) * 512], 16, 0, 0);
        __builtin_amdgcn_global_load_lds(
            (const __attribute__((address_space(1))) void*)(vg + (size_t)it * 32 * LL),
            (__attribute__((address_space(3))) void*)&VtS[0][(it * 4 + w) * 512], 16, 0, 0);
    }
    if (tid < 64) smaskS[0][tid] = (pb[tid] != 0) & (cb[tid] != 0);
    __syncthreads();

    f32x16 O0, O1;
    #pragma unroll
    for (int e = 0; e < 16; ++e) { O0[e] = 0.f; O1[e] = 0.f; }
    float mrun = -INFINITY, mkc = -INFINITY, lrun = 0.f;

    for (int kt = 0; kt < 16; ++kt) {
        int buf = kt & 1;
        if (kt < 15) {
            int k0n = (kt + 1) * 64;
            #pragma unroll
            for (int it = 0; it < 2; ++it) {
                __builtin_amdgcn_global_load_lds(
                    (const __attribute__((address_space(1))) void*)(kg + (size_t)(k0n + it * 32) * DD),
                    (__attribute__((address_space(3))) void*)&KsS[buf ^ 1][(it * 4 + w) * 512], 16, 0, 0);
                __builtin_amdgcn_global_load_lds(
                    (const __attribute__((address_space(1))) void*)(vg + k0n + (size_t)it * 32 * LL),
                    (__attribute__((address_space(3))) void*)&VtS[buf ^ 1][(it * 4 + w) * 512], 16, 0, 0);
            }
            if (tid < 64)
                smaskS[buf ^ 1][tid] = (pb[k0n + tid] != 0) & (cb[k0n + tid] != 0);
        }

        const short* Kb = KsS[buf];
        const short* Vb = VtS[buf];
        int rsw = q5 & 7;

        // hoisted loads: K frags, V frags, mask int4s — all issued up front
        short8 Ka0[4], Ka1[4], Va0[4], Va1[4];
        #pragma unroll
        for (int i = 0; i < 4; ++i) {
            int off = ((2 * i + hi) ^ rsw) << 3;
            Ka0[i] = *(const short8*)&Kb[q5 * 64 + off];
            Ka1[i] = *(const short8*)&Kb[(32 + q5) * 64 + off];
            Va0[i] = *(const short8*)&Vb[q5 * 64 + off];
            Va1[i] = *(const short8*)&Vb[(32 + q5) * 64 + off];
        }
        const int4v* mi = (const int4v*)&smaskS[buf][0];
        int4v mg0[4], mg1[4];
        #pragma unroll
        for (int a = 0; a < 4; ++a) {
            mg0[a] = mi[2 * a + hi];       // ints 8a+4hi .. +3
            mg1[a] = mi[8 + 2 * a + hi];
        }

        f32x16 S0, S1;
        #pragma unroll
        for (int e = 0; e < 16; ++e) { S0[e] = 0.f; S1[e] = 0.f; }
        __builtin_amdgcn_s_setprio(1);
        #pragma unroll
        for (int i = 0; i < 4; ++i) {
            S0 = __builtin_amdgcn_mfma_f32_32x32x16_bf16(Ka0[i], Qf[i], S0, 0, 0, 0);
            S1 = __builtin_amdgcn_mfma_f32_32x32x16_bf16(Ka1[i], Qf[i], S1, 0, 0, 0);
        }
        __builtin_amdgcn_s_setprio(0);

        // mask: s[4a+j] masked iff mg[a][j]
        float s[32];
        #pragma unroll
        for (int a = 0; a < 4; ++a) {
            #pragma unroll
            for (int j = 0; j < 4; ++j) {
                s[4 * a + j]      = mg0[a][j] ? -1e20f : S0[4 * a + j];
                s[16 + 4 * a + j] = mg1[a][j] ? -1e20f : S1[4 * a + j];
            }
        }

        // row max (max3-friendly tree) + cross-half shfl
        float m16[16];
        #pragma unroll
        for (int r = 0; r < 16; ++r) m16[r] = fmaxf(s[r], s[r + 16]);
        float a0 = fmaxf(fmaxf(m16[0], m16[1]), m16[2]);
        float a1 = fmaxf(fmaxf(m16[3], m16[4]), m16[5]);
        float a2 = fmaxf(fmaxf(m16[6], m16[7]), m16[8]);
        float a3 = fmaxf(fmaxf(m16[9], m16[10]), m16[11]);
        float a4 = fmaxf(fmaxf(m16[12], m16[13]), m16[14]);
        float mx = fmaxf(fmaxf(fmaxf(a0, a1), fmaxf(a2, a3)), fmaxf(a4, m16[15]));
        mx = fmaxf(mx, __shfl_xor(mx, 32, 64));

        // defer-max: rescale only if some row's max grew past threshold
        if (__any(mx > mrun + THRL)) {
            float mnew = fmaxf(mrun, mx);
            float nk = mnew * K2C;
            float sc = exp2f(mkc - nk);
            lrun *= sc;
            #pragma unroll
            for (int e = 0; e < 16; ++e) { O0[e] *= sc; O1[e] *= sc; }
            mrun = mnew;
            mkc = nk;
        }

        float pv[32];
        #pragma unroll
        for (int r = 0; r < 32; ++r) pv[r] = exp2f(__builtin_fmaf(s[r], K2C, -mkc));

        float t16[16];
        #pragma unroll
        for (int r = 0; r < 16; ++r) t16[r] = pv[r] + pv[r + 16];
        float t8[8];
        #pragma unroll
        for (int r = 0; r < 8; ++r) t8[r] = t16[r] + t16[r + 8];
        float rs = ((t8[0] + t8[1]) + (t8[2] + t8[3])) + ((t8[4] + t8[5]) + (t8[6] + t8[7]));
        rs += __shfl_xor(rs, 32, 64);
        lrun += rs;

        // pack P -> B-fragments via cvt_pk + permlane32_swap
        union PW { int4v i4; short8 s8; } pa[4];
        #pragma unroll
        for (int st = 0; st < 2; ++st) {
            int c0, d0, c1, d1, c2, d2, c3, d3;
            CVTPK(c0, pv[16 * st + 0], pv[16 * st + 1]);
            CVTPK(d0, pv[16 * st + 4], pv[16 * st + 5]);
            PLSWAP(c0, d0);
            CVTPK(c1, pv[16 * st + 2], pv[16 * st + 3]);
            CVTPK(d1, pv[16 * st + 6], pv[16 * st + 7]);
            PLSWAP(c1, d1);
            pa[2 * st].i4 = (int4v){c0, c1, d0, d1};
            CVTPK(c2, pv[16 * st + 8], pv[16 * st + 9]);
            CVTPK(d2, pv[16 * st + 12], pv[16 * st + 13]);
            PLSWAP(c2, d2);
            CVTPK(c3, pv[16 * st + 10], pv[16 * st + 11]);
            CVTPK(d3, pv[16 * st + 14], pv[16 * st + 15]);
            PLSWAP(c3, d3);
            pa[2 * st + 1].i4 = (int4v){c2, c3, d2, d3};
        }

        __builtin_amdgcn_s_setprio(1);
        #pragma unroll
        for (int ks = 0; ks < 4; ++ks) {
            O0 = __builtin_amdgcn_mfma_f32_32x32x16_bf16(Va0[ks], pa[ks].s8, O0, 0, 0, 0);
            O1 = __builtin_amdgcn_mfma_f32_32x32x16_bf16(Va1[ks], pa[ks].s8, O1, 0, 0, 0);
        }
        __builtin_amdgcn_s_setprio(0);

        if (kt < 15) __syncthreads();
    }

    // epilogue: per-wave transpose O^T -> row-major via private LDS region
    float invl = 1.f / lrun;
    float* oreg = OutS[w];
    int orow = lane >> 1;
    int ocol = (lane & 1) * 16;

    #pragma unroll
    for (int r = 0; r < 16; ++r) {
        int dl = (r & 3) + 8 * (r >> 2) + 4 * hi;
        oreg[q5 * 36 + dl] = O0[r];
    }
    if (hi == 0) oreg[q5 * 36 + 32] = invl;
    asm volatile("" ::: "memory");
    {
        float iv = oreg[orow * 36 + 32];
        float* gout = out + ((size_t)b * LL + q0w + orow) * EE + h * DD + ocol;
        #pragma unroll
        for (int c = 0; c < 4; ++c) {
            float4 vv = *(float4*)&oreg[orow * 36 + ocol + 4 * c];
            vv.x *= iv; vv.y *= iv; vv.z *= iv; vv.w *= iv;
            *(float4*)&gout[4 * c] = vv;
        }
    }
    asm volatile("" ::: "memory");
    #pragma unroll
    for (int r = 0; r < 16; ++r) {
        int dl = (r & 3) + 8 * (r >> 2) + 4 * hi;
        oreg[q5 * 36 + dl] = O1[r];
    }
    asm volatile("" ::: "memory");
    {
        float iv = oreg[orow * 36 + 32];
        float* gout = out + ((size_t)b * LL + q0w + orow) * EE + h * DD + 32 + ocol;
        #pragma unroll
        for (int c = 0; c < 4; ++c) {
            float4 vv = *(float4*)&oreg[orow * 36 + ocol + 4 * c];
            vv.x *= iv; vv.y *= iv; vv.z *= iv; vv.w *= iv;
            *(float4*)&gout[4 * c] = vv;
        }
    }
}

extern "C" void kernel_launch(void* const* d_in, const int* in_sizes, int n_in,
                              void* d_out, int out_size, void* d_ws, size_t ws_size,
                              hipStream_t stream) {
    const float* query = (const float*)d_in[0];
    const float* keys  = (const float*)d_in[1];
    const float* values = (const float*)d_in[2];
    const int* pad  = (const int*)d_in[3];
    const int* cau  = (const int*)d_in[4];
    const int* bern = (const int*)d_in[5];
    const float* conv_w = (const float*)d_in[6];
    const float* conv_b = (const float*)d_in[7];
    const float* Wv = (const float*)d_in[8];
    float* outp = (float*)d_out;

    const size_t per = (size_t)BB * HH * LL * DD;
    __hip_bfloat16* qcb = (__hip_bfloat16*)d_ws;
    __hip_bfloat16* ksb = qcb + per;
    __hip_bfloat16* vtb = ksb + per;
    float* pmax = (float*)(vtb + per);
    float* psum = pmax + (size_t)BB * HH * NCH * 64;

    conv_kernel<<<BB * HH * (LL / 4), 256, 0, stream>>>(query, conv_w, conv_b, qcb);
    ksm_partial_kernel<<<BB * HH * NCH, 256, 0, stream>>>(keys, bern, pmax, psum);
    ksm_final_kernel<<<BB * HH * NCH, 256, 0, stream>>>(keys, bern, pmax, psum, ksb);
    vlin_kernel<<<BB * HH * (LL / 64), 256, 0, stream>>>(values, Wv, vtb);
    attn_mfma_kernel<<<BB * HH * 8, 256, 0, stream>>>(qcb, ksb, vtb, pad, cau, outp);
}